// Round 2
// baseline (142.398 us; speedup 1.0000x reference)
//
#include <hip/hip_runtime.h>

// SNN: 3 LIF layers, B=2097152 rows, widths 2 -> 2 -> 3 -> 2.
// Memory-bound problem (~151 MB total traffic -> ~24 us roofline @ 6.3 TB/s).
//
// Round-2 hardening:
//  * Every global store is bounds-checked against out_size (harness-provided),
//    so no write can ever leave d_out even if the 9*B layout assumption is off.
//  * Arithmetic mirrors numpy bit-for-bit: __fmul_rn/__fadd_rn in numpy's
//    association order, no fma contraction -> no borderline threshold flips.
//  * One row per thread, scalar loads/stores (boring and obviously pure).

#define BETA 0.90483741803595952f   // exp(-1/10)
#define THR  15.0f

// reference lif_step (reset_mechanism='zero'):
//   reset = (mem_prev > 15) ? 1 : 0
//   base  = beta*mem_prev + cur          (numpy: round(beta*mem) then round(+cur))
//   mem   = base * (1 - reset)           (exact: *1.0 or *0.0)
//   spk   = (mem - 15 > 0) ? 1 : 0       (== mem > 15)
__device__ __forceinline__ void lif(float cur, float mem_prev, float& nm, float& spk) {
    float base = __fadd_rn(__fmul_rn(BETA, mem_prev), cur);
    nm  = (mem_prev > THR) ? 0.0f : base;
    spk = (nm > THR) ? 1.0f : 0.0f;
}

__global__ __launch_bounds__(256) void snn_kernel(
    const float* __restrict__ x,
    const float* __restrict__ mem1,
    const float* __restrict__ mem2,
    const float* __restrict__ mem3,
    const float* __restrict__ W1,   // [2,2] row-major [out,in]
    const float* __restrict__ W2,   // [3,2]
    const float* __restrict__ W3,   // [2,3]
    float* __restrict__ out,        // spk3[2B] | mem1[2B] | mem2[3B] | mem3[2B]
    int B,
    long long out_n)                // element count of d_out — hard bound on stores
{
    const long long t = (long long)blockIdx.x * blockDim.x + threadIdx.x;
    if (t >= B) return;

    // weights (22 floats, L1/L2 cached)
    const float w1_00 = W1[0], w1_01 = W1[1], w1_10 = W1[2], w1_11 = W1[3];
    const float w2_00 = W2[0], w2_01 = W2[1],
                w2_10 = W2[2], w2_11 = W2[3],
                w2_20 = W2[4], w2_21 = W2[5];
    const float w3_00 = W3[0], w3_01 = W3[1], w3_02 = W3[2],
                w3_10 = W3[3], w3_11 = W3[4], w3_12 = W3[5];

    const float x0 = x[2 * t], x1 = x[2 * t + 1];
    const float m1a = mem1[2 * t], m1b = mem1[2 * t + 1];
    const float m2a = mem2[3 * t], m2b = mem2[3 * t + 1], m2c = mem2[3 * t + 2];
    const float m3a = mem3[2 * t], m3b = mem3[2 * t + 1];

    // layer 1: cur1 = x @ W1^T   (numpy order: round(x0*w) + round(x1*w))
    float cur1_0 = __fadd_rn(__fmul_rn(x0, w1_00), __fmul_rn(x1, w1_01));
    float cur1_1 = __fadd_rn(__fmul_rn(x0, w1_10), __fmul_rn(x1, w1_11));
    float m1o_0, m1o_1, s1_0, s1_1;
    lif(cur1_0, m1a, m1o_0, s1_0);
    lif(cur1_1, m1b, m1o_1, s1_1);

    // layer 2: cur2 = spk1 @ W2^T
    float cur2_0 = __fadd_rn(__fmul_rn(s1_0, w2_00), __fmul_rn(s1_1, w2_01));
    float cur2_1 = __fadd_rn(__fmul_rn(s1_0, w2_10), __fmul_rn(s1_1, w2_11));
    float cur2_2 = __fadd_rn(__fmul_rn(s1_0, w2_20), __fmul_rn(s1_1, w2_21));
    float m2o_0, m2o_1, m2o_2, s2_0, s2_1, s2_2;
    lif(cur2_0, m2a, m2o_0, s2_0);
    lif(cur2_1, m2b, m2o_1, s2_1);
    lif(cur2_2, m2c, m2o_2, s2_2);

    // layer 3: cur3 = spk2 @ W3^T  (numpy left-assoc 3-term sum)
    float cur3_0 = __fadd_rn(__fadd_rn(__fmul_rn(s2_0, w3_00), __fmul_rn(s2_1, w3_01)),
                             __fmul_rn(s2_2, w3_02));
    float cur3_1 = __fadd_rn(__fadd_rn(__fmul_rn(s2_0, w3_10), __fmul_rn(s2_1, w3_11)),
                             __fmul_rn(s2_2, w3_12));
    float m3o_0, m3o_1, s3_0, s3_1;
    lif(cur3_0, m3a, m3o_0, s3_0);
    lif(cur3_1, m3b, m3o_1, s3_1);

    // stores: out = spk3[2B] | mem1[2B] | mem2[3B] | mem3[2B]; every index
    // bounds-checked against out_n so no write can escape d_out.
    const long long Bl = B;
    long long i;
    i = 2 * t;               if (i + 1 < out_n) { out[i] = s3_0;  out[i + 1] = s3_1; }
    i = 2 * Bl + 2 * t;      if (i + 1 < out_n) { out[i] = m1o_0; out[i + 1] = m1o_1; }
    i = 4 * Bl + 3 * t;      if (i + 2 < out_n) { out[i] = m2o_0; out[i + 1] = m2o_1; out[i + 2] = m2o_2; }
    i = 7 * Bl + 2 * t;      if (i + 1 < out_n) { out[i] = m3o_0; out[i + 1] = m3o_1; }
}

extern "C" void kernel_launch(void* const* d_in, const int* in_sizes, int n_in,
                              void* d_out, int out_size, void* d_ws, size_t ws_size,
                              hipStream_t stream) {
    const float* x    = (const float*)d_in[0];
    const float* mem1 = (const float*)d_in[1];
    const float* mem2 = (const float*)d_in[2];
    const float* mem3 = (const float*)d_in[3];
    const float* W1   = (const float*)d_in[4];
    const float* W2   = (const float*)d_in[5];
    const float* W3   = (const float*)d_in[6];
    float* out        = (float*)d_out;

    const int B = in_sizes[0] / 2;           // x is [B,2]
    const int block = 256;
    const int grid = (B + block - 1) / block;

    snn_kernel<<<grid, block, 0, stream>>>(x, mem1, mem2, mem3, W1, W2, W3,
                                           out, B, (long long)out_size);
}